// Round 9
// baseline (192.692 us; speedup 1.0000x reference)
//
#include <hip/hip_runtime.h>
#include <math.h>

#define PP 4096   // P = H*W
#define CC 256    // channels
#define NN 2      // batch
#define NSTEP 16  // 4096 q-rows / 256 per step (16 rows per wave per step)

typedef __attribute__((ext_vector_type(4))) float f32x4;
typedef __attribute__((ext_vector_type(8))) int i32x8;
typedef __attribute__((ext_vector_type(2))) int i32x2;

// [journal r18: r8 (16 waves) only -2.8us; strip ~40us vs ~16us floor. Staging
//  path was the wall: per-wave gld_lds streams at ~27 B/cy/CU (vs m97's ~50)
//  + LDS round-trip + asm vmcnt gate. Fix: MX A-fragment is wave-private and
//  register-sized -- load A DIRECTLY to VGPRs (global_load_dwordx2, one base
//  + imm offsets, 1-step software pipeline in plain C; compiler emits counted
//  vmcnt). No LDS for A/B at all; no inline asm in the hot loop.]
// [journal r16/r17: MFMA cost is per-SIMD (~34.6 cy MX 16x16x128). MX-scaled
//  + VALU diet validated absmax 0.0. 16 waves x 16 rows, 4 waves/SIMD.]
// [journal r13: per-block agent-scope ACQ_REL fences cost +40us (fence
//  storm). Strip kernel: block-local stats, ONE atomicAdd per block.]
// [journal r11/r12: hipLaunchCooperativeKernel NOT graph-capture-safe here;
//  grid.sync does NOT flush cross-XCD L2. Do not retry cooperative fusion.]

// ---- kernel 1: meanT[c] = mean over (n,p) of T (float4 loads); init loss ----
__global__ __launch_bounds__(256) void mean_kernel(const float* __restrict__ T,
                                                   float* __restrict__ meanT,
                                                   float* __restrict__ loss_acc) {
    int c = blockIdx.x, tid = threadIdx.x;
    float s = 0.f;
    for (int n = 0; n < NN; n++) {
        const float4* Tc = (const float4*)&T[(size_t)(n * CC + c) * PP];
        for (int g = 0; g < 4; g++) {
            float4 v = Tc[tid + g * 256];
            s += (v.x + v.y) + (v.z + v.w);
        }
    }
    __shared__ float red[256];
    red[tid] = s; __syncthreads();
    for (int st = 128; st > 0; st >>= 1) {
        if (tid < st) red[tid] += red[tid + st];
        __syncthreads();
    }
    if (tid == 0) meanT[c] = red[0] * (1.0f / (NN * PP));
    if (blockIdx.x == 0 && tid < NN) loss_acc[tid] = 0.f;
}

// ---- kernel 2: center by meanT, L2-normalize over C, write FP8 e4m3 [n][p][c] ----
__global__ __launch_bounds__(256) void normalize_kernel(const float* __restrict__ I,
                                                        const float* __restrict__ T,
                                                        const float* __restrict__ meanT,
                                                        char* __restrict__ InT,
                                                        char* __restrict__ TnT) {
    int pc = blockIdx.x * 32;      // 32 positions per block
    int n = blockIdx.y;
    int which = blockIdx.z;        // 0: I -> InT, 1: T -> TnT
    const float* X = which ? T : I;
    char* Y = which ? TnT : InT;

    __shared__ float tile[CC][36];   // [c][p_local], pad 36 (16B-aligned rows)
    __shared__ float red[32][32];    // [c-group][p_local]
    __shared__ float invn[32];

    int tid = threadIdx.x;
    int pl4 = tid & 7, c0 = tid >> 3;   // 32 c-groups x 8 p-quads
    float sq0 = 0.f, sq1 = 0.f, sq2 = 0.f, sq3 = 0.f;
    for (int c = c0; c < CC; c += 32) {
        float m = meanT[c];
        float4 v = *(const float4*)&X[(size_t)(n * CC + c) * PP + pc + pl4 * 4];
        v.x -= m; v.y -= m; v.z -= m; v.w -= m;
        *(float4*)&tile[c][pl4 * 4] = v;
        sq0 += v.x * v.x; sq1 += v.y * v.y; sq2 += v.z * v.z; sq3 += v.w * v.w;
    }
    red[c0][pl4 * 4 + 0] = sq0;
    red[c0][pl4 * 4 + 1] = sq1;
    red[c0][pl4 * 4 + 2] = sq2;
    red[c0][pl4 * 4 + 3] = sq3;
    __syncthreads();
    if (tid < 32) {
        float s = 0.f;
        for (int k = 0; k < 32; k++) s += red[k][tid];
        invn[tid] = 1.0f / sqrtf(s);
    }
    __syncthreads();
    for (int pass = 0; pass < 8; pass++) {
        int r = pass * 4 + (tid >> 6);
        int c4 = (tid & 63) * 4;
        float in = invn[r];
        float v0 = tile[c4 + 0][r] * in;
        float v1 = tile[c4 + 1][r] * in;
        float v2 = tile[c4 + 2][r] * in;
        float v3 = tile[c4 + 3][r] * in;
        int w = __builtin_amdgcn_cvt_pk_fp8_f32(v0, v1, 0, false);
        w = __builtin_amdgcn_cvt_pk_fp8_f32(v2, v3, w, true);
        *(unsigned*)&Y[(size_t)(n * PP + pc + r) * CC + c4] = (unsigned)w;
    }
}

// ---- kernel 3: strip kernel -- block owns 32 p-cols x all 4096 q; 16 waves
// x 16 A-rows each (4 waves/SIMD). All MFMA operands load DIRECTLY to VGPRs:
// lane (lm,quad) reads row lm bytes {kb*128 + j*32 + quad*8} -- the exact MX
// 16x16x128 fragment layout (validated bitwise vs the LDS version, absmax 0).
// Pass 0: col-max of dot (== col-min of raw) block-locally. Pass 1: recompute
// dots, w = exp2(fma(dot, inv2/2, 14.427-inv2/2)), col-sums + diag, ONE
// atomicAdd per block. 1-step register software pipeline (cur/nxt); compiler
// emits the counted vmcnt (cur's loads are older than nxt's). No LDS for
// A/B; only 2.3 KB reduction scratch.
__global__ __launch_bounds__(1024) void cx_strip(const char* __restrict__ TnT,
                                                 const char* __restrict__ InT,
                                                 float* __restrict__ loss_acc) {
    const int strip = blockIdx.x;       // 0..127
    const int n = blockIdx.y;
    const int p0 = strip * 32;
    const char* __restrict__ Ab = TnT + (size_t)n * PP * CC;            // q rows
    const char* __restrict__ Bb = InT + (size_t)n * PP * CC + (size_t)p0 * CC;

    __shared__ float redw[16][32];
    __shared__ float inv2s[32];
    __shared__ float dwl[32];

    const int tid = threadIdx.x;
    const int l = tid & 63, wv = tid >> 6;          // wv 0..15
    const int lm = l & 15, quad = l >> 4;

    // ---- B fragments to registers: bf.v[ct][kb] (32 VGPR) ----
    union BU { i32x2 d[2][2][4]; i32x8 v[2][2]; } bf;
#pragma unroll
    for (int ct = 0; ct < 2; ct++)
#pragma unroll
        for (int kb = 0; kb < 2; kb++)
#pragma unroll
            for (int j = 0; j < 4; j++)
                bf.d[ct][kb][j] = *(const i32x2*)(Bb + (ct * 16 + lm) * 256 +
                                                  kb * 128 + j * 32 + quad * 8);

    // per-lane A base: row (wv*16+lm), byte quad*8; step qs at +qs*65536,
    // granule (kb,j) at +kb*128+j*32 (immediate offsets)
    const char* Abase = Ab + (size_t)(wv * 16 + lm) * 256 + quad * 8;
    union AU { i32x2 d[2][4]; i32x8 v[2]; };

    float amax[2] = {-3.4e38f, -3.4e38f};
    float hc[2] = {0.f, 0.f}, c0c[2] = {0.f, 0.f};
    float ss[2] = {0.f, 0.f};
    // diag for col p0+ct*16+lm lives at global q = p0+ct*16+lm:
    const int qdd0 = p0 >> 8, wdd0 = (p0 >> 4) & 15;
    const int qdd1 = (p0 + 16) >> 8, wdd1 = ((p0 + 16) >> 4) & 15;

#pragma unroll 1
    for (int pass = 0; pass < 2; pass++) {
        AU cur, nxt;
#pragma unroll
        for (int kb = 0; kb < 2; kb++)
#pragma unroll
            for (int j = 0; j < 4; j++)
                cur.d[kb][j] = *(const i32x2*)(Abase + kb * 128 + j * 32);

#pragma unroll 2
        for (int qs = 0; qs < NSTEP; qs++) {
            if (qs < NSTEP - 1) {
#pragma unroll
                for (int kb = 0; kb < 2; kb++)
#pragma unroll
                    for (int j = 0; j < 4; j++)
                        nxt.d[kb][j] = *(const i32x2*)(Abase +
                            (size_t)(qs + 1) * 65536 + kb * 128 + j * 32);
            }

            f32x4 acc[2] = {};
#pragma unroll
            for (int kb = 0; kb < 2; kb++)
#pragma unroll
                for (int ct = 0; ct < 2; ct++)
                    acc[ct] = __builtin_amdgcn_mfma_scale_f32_16x16x128_f8f6f4(
                        cur.v[kb], bf.v[ct][kb], acc[ct],
                        0, 0,                // cbsz=0 (e4m3), blgp=0 (e4m3)
                        0, 0x7f7f7f7f,       // scale_a sel, 1.0
                        0, 0x7f7f7f7f);      // scale_b sel, 1.0

            if (pass == 0) {
#pragma unroll
                for (int ct = 0; ct < 2; ct++)
#pragma unroll
                    for (int e = 0; e < 4; e++)
                        amax[ct] = fmaxf(amax[ct], acc[ct][e]);
            } else {
#pragma unroll
                for (int ct = 0; ct < 2; ct++) {
                    float s2 = 0.f;
#pragma unroll
                    for (int e = 0; e < 4; e++)
                        s2 += exp2f(fmaf(acc[ct][e], hc[ct], c0c[ct]));
                    ss[ct] += s2;
                }
                // diag: local row quad*4+e == lm  <=>  quad==lm>>2, e==lm&3
                if (qs == qdd0 && wv == wdd0 && quad == (lm >> 2))
                    dwl[lm] = exp2f(fmaf(acc[0][lm & 3], hc[0], c0c[0]));
                if (qs == qdd1 && wv == wdd1 && quad == (lm >> 2))
                    dwl[16 + lm] = exp2f(fmaf(acc[1][lm & 3], hc[1], c0c[1]));
            }

            if (qs < NSTEP - 1) cur = nxt;
        }

        if (pass == 0) {  // reduce col-maxes -> exp2 coefs per col
#pragma unroll
            for (int ct = 0; ct < 2; ct++) {
                amax[ct] = fmaxf(amax[ct], __shfl_xor(amax[ct], 16));
                amax[ct] = fmaxf(amax[ct], __shfl_xor(amax[ct], 32));
                if (quad == 0) redw[wv][ct * 16 + lm] = amax[ct];
            }
            __syncthreads();
            if (tid < 32) {
                float mx = redw[0][tid];
#pragma unroll
                for (int w2 = 1; w2 < 16; w2++) mx = fmaxf(mx, redw[w2][tid]);
                float mnv = (1.0f - mx) * 0.5f;            // column min of raw
                inv2s[tid] = 14.4269504f / (mnv + 1e-5f);
            }
            __syncthreads();
            {
                float i20 = inv2s[lm], i21 = inv2s[16 + lm];
                hc[0] = i20 * 0.5f; c0c[0] = 14.4269504f - hc[0];
                hc[1] = i21 * 0.5f; c0c[1] = 14.4269504f - hc[1];
            }
        }
    }

    // final: S per col, then partial loss = sum_c dwl[c]/S[c], one atomicAdd
#pragma unroll
    for (int ct = 0; ct < 2; ct++) {
        ss[ct] += __shfl_xor(ss[ct], 16);
        ss[ct] += __shfl_xor(ss[ct], 32);
        if (quad == 0) redw[wv][ct * 16 + lm] = ss[ct];
    }
    __syncthreads();
    if (tid < 32) {
        float s = 0.f;
#pragma unroll
        for (int w2 = 0; w2 < 16; w2++) s += redw[w2][tid];
        float part = dwl[tid] / s;
        part += __shfl_xor(part, 1);
        part += __shfl_xor(part, 2);
        part += __shfl_xor(part, 4);
        part += __shfl_xor(part, 8);
        part += __shfl_xor(part, 16);
        if (tid == 0) atomicAdd(&loss_acc[n], part);
    }
}

// ---- kernel 4: loss = mean_n -log(0.5 + 0.5 * acc_n/P) ----
__global__ void finalize_kernel(const float* __restrict__ loss_acc,
                                float* __restrict__ out) {
    float m0 = 0.5f + 0.5f * (loss_acc[0] / (float)PP);
    float m1 = 0.5f + 0.5f * (loss_acc[1] / (float)PP);
    out[0] = 0.5f * (-logf(m0) - logf(m1));
}

extern "C" void kernel_launch(void* const* d_in, const int* in_sizes, int n_in,
                              void* d_out, int out_size, void* d_ws, size_t ws_size,
                              hipStream_t stream) {
    const float* I = (const float*)d_in[0];
    const float* T = (const float*)d_in[1];
    float* out = (float*)d_out;

    char* ws = (char*)d_ws;
    const size_t SZ_F8 = (size_t)NN * PP * CC;  // 2 MB each (fp8)
    char* InT = ws;
    char* TnT = ws + SZ_F8;
    float* meanT = (float*)(ws + 2 * SZ_F8);               // 1 KB
    float* loss_acc = (float*)(ws + 2 * SZ_F8 + 32768);    // 8 B

    mean_kernel<<<CC, 256, 0, stream>>>(T, meanT, loss_acc);
    normalize_kernel<<<dim3(PP / 32, NN, 2), 256, 0, stream>>>(I, T, meanT, InT, TnT);
    cx_strip<<<dim3(PP / 32, NN), 1024, 0, stream>>>(TnT, InT, loss_acc);
    finalize_kernel<<<1, 1, 0, stream>>>(loss_acc, out);
}

// Round 10
// 109.985 us; speedup vs baseline: 1.7520x; 1.7520x over previous
//
#include <hip/hip_runtime.h>
#include <math.h>

#define PP 4096   // P = H*W
#define CC 256    // channels
#define NN 2      // batch
#define NSTEP 16  // 4096 q-rows / 256 per step (16 rows per wave per step)

typedef __attribute__((ext_vector_type(4))) float f32x4;
typedef __attribute__((ext_vector_type(8))) int i32x8;
typedef __attribute__((ext_vector_type(2))) int i32x2;

// [journal r19: r9 (direct VGPR loads from row-major fp8) regressed 40->123us:
//  the fragment gather (16 lanes x 256B-strided rows x 8B) fragments every
//  load into 16 transactions at 50% line use -- request-rate bound (MfmaUtil
//  5%). Fix: WE OWN the intermediate layout -- normalize now writes
//  fragment-major: addr(p,c) = (p>>4)*4096 + (c>>5)*512 + ((c>>3)&3)*128 +
//  (p&15)*8 + (c&7). Strip fragment load = base + g*512 + lane*8: 512B
//  contiguous per instr, registers only, no LDS, no asm. Same bytes -> same
//  MFMA -> absmax 0.0 preserved.]
// [journal r16/r17: MFMA cost is per-SIMD (~34.6 cy MX 16x16x128). MX-scaled
//  + VALU diet validated absmax 0.0. 16 waves x 16 rows, 4 waves/SIMD.]
// [journal r13: per-block agent-scope ACQ_REL fences cost +40us. Strip:
//  block-local stats, ONE atomicAdd per block.]
// [journal r11/r12: hipLaunchCooperativeKernel NOT graph-capture-safe here;
//  grid.sync does NOT flush cross-XCD L2. Do not retry cooperative fusion.]

// ---- kernel 1: meanT[c] = mean over (n,p) of T (float4 loads); init loss ----
__global__ __launch_bounds__(256) void mean_kernel(const float* __restrict__ T,
                                                   float* __restrict__ meanT,
                                                   float* __restrict__ loss_acc) {
    int c = blockIdx.x, tid = threadIdx.x;
    float s = 0.f;
    for (int n = 0; n < NN; n++) {
        const float4* Tc = (const float4*)&T[(size_t)(n * CC + c) * PP];
        for (int g = 0; g < 4; g++) {
            float4 v = Tc[tid + g * 256];
            s += (v.x + v.y) + (v.z + v.w);
        }
    }
    __shared__ float red[256];
    red[tid] = s; __syncthreads();
    for (int st = 128; st > 0; st >>= 1) {
        if (tid < st) red[tid] += red[tid + st];
        __syncthreads();
    }
    if (tid == 0) meanT[c] = red[0] * (1.0f / (NN * PP));
    if (blockIdx.x == 0 && tid < NN) loss_acc[tid] = 0.f;
}

// ---- kernel 2: center, L2-normalize over C, write FP8 e4m3 FRAGMENT-MAJOR ----
// addr(p,c) = (p>>4)*4096 + (c>>5)*512 + ((c>>3)&3)*128 + (p&15)*8 + (c&7)
// (4 consecutive channels stay within one 8B granule -> single 4B store)
__global__ __launch_bounds__(256) void normalize_kernel(const float* __restrict__ I,
                                                        const float* __restrict__ T,
                                                        const float* __restrict__ meanT,
                                                        char* __restrict__ InT,
                                                        char* __restrict__ TnT) {
    int pc = blockIdx.x * 32;      // 32 positions per block
    int n = blockIdx.y;
    int which = blockIdx.z;        // 0: I -> InT, 1: T -> TnT
    const float* X = which ? T : I;
    char* Y = (which ? TnT : InT) + (size_t)n * PP * CC;

    __shared__ float tile[CC][36];   // [c][p_local], pad 36 (16B-aligned rows)
    __shared__ float red[32][32];    // [c-group][p_local]
    __shared__ float invn[32];

    int tid = threadIdx.x;
    int pl4 = tid & 7, c0 = tid >> 3;   // 32 c-groups x 8 p-quads
    float sq0 = 0.f, sq1 = 0.f, sq2 = 0.f, sq3 = 0.f;
    for (int c = c0; c < CC; c += 32) {
        float m = meanT[c];
        float4 v = *(const float4*)&X[(size_t)(n * CC + c) * PP + pc + pl4 * 4];
        v.x -= m; v.y -= m; v.z -= m; v.w -= m;
        *(float4*)&tile[c][pl4 * 4] = v;
        sq0 += v.x * v.x; sq1 += v.y * v.y; sq2 += v.z * v.z; sq3 += v.w * v.w;
    }
    red[c0][pl4 * 4 + 0] = sq0;
    red[c0][pl4 * 4 + 1] = sq1;
    red[c0][pl4 * 4 + 2] = sq2;
    red[c0][pl4 * 4 + 3] = sq3;
    __syncthreads();
    if (tid < 32) {
        float s = 0.f;
        for (int k = 0; k < 32; k++) s += red[k][tid];
        invn[tid] = 1.0f / sqrtf(s);
    }
    __syncthreads();
    for (int pass = 0; pass < 8; pass++) {
        int r = pass * 4 + (tid >> 6);
        int p = pc + r;
        int c4 = (tid & 63) * 4;
        float in = invn[r];
        float v0 = tile[c4 + 0][r] * in;
        float v1 = tile[c4 + 1][r] * in;
        float v2 = tile[c4 + 2][r] * in;
        float v3 = tile[c4 + 3][r] * in;
        int w = __builtin_amdgcn_cvt_pk_fp8_f32(v0, v1, 0, false);
        w = __builtin_amdgcn_cvt_pk_fp8_f32(v2, v3, w, true);
        size_t addr = (size_t)(p >> 4) * 4096 + (c4 >> 5) * 512 +
                      ((c4 >> 3) & 3) * 128 + (p & 15) * 8 + (c4 & 7);
        *(unsigned*)&Y[addr] = (unsigned)w;
    }
}

// ---- kernel 3: strip kernel -- block owns 32 p-cols x all 4096 q; 16 waves
// x 16 A-rows each (4 waves/SIMD). Fragment-major input: each (kb,j) operand
// slice loads as base + g*512 + lane*8 (512B contiguous / wave / instr),
// directly to VGPRs. Pass 0: col-max of dot block-locally. Pass 1: recompute
// dots, w = exp2(fma(dot, inv2/2, 14.427-inv2/2)), col-sums + diag, ONE
// atomicAdd per block. 1-step register pipeline (cur/nxt), compiler-counted
// vmcnt. No LDS for A/B; 2.3 KB reduction scratch only.
__global__ __launch_bounds__(1024) void cx_strip(const char* __restrict__ TnT,
                                                 const char* __restrict__ InT,
                                                 float* __restrict__ loss_acc) {
    const int strip = blockIdx.x;       // 0..127
    const int n = blockIdx.y;
    const int p0 = strip * 32;
    const char* __restrict__ Ab = TnT + (size_t)n * PP * CC;  // frag-major
    const char* __restrict__ Bb = InT + (size_t)n * PP * CC;  // frag-major

    __shared__ float redw[16][32];
    __shared__ float inv2s[32];
    __shared__ float dwl[32];

    const int tid = threadIdx.x;
    const int l = tid & 63, wv = tid >> 6;          // wv 0..15
    const int lm = l & 15, quad = l >> 4;

    // ---- B fragments to registers: bf.v[ct][kb] (32 VGPR) ----
    // row-group (p0>>4)+ct = strip*2+ct; granule g=kb*4+j; lane offset l*8
    union BU { i32x2 d[2][8]; i32x8 v[2][2]; } bf;
#pragma unroll
    for (int ct = 0; ct < 2; ct++)
#pragma unroll
        for (int g = 0; g < 8; g++)
            bf.d[ct][g] = *(const i32x2*)(Bb + (size_t)(strip * 2 + ct) * 4096 +
                                          g * 512 + l * 8);

    // per-wave A base: row-group wv (of step 0); step qs at +qs*65536
    const char* Abase = Ab + (size_t)wv * 4096 + l * 8;
    union AU { i32x2 d[8]; i32x8 v[2]; };

    float amax[2] = {-3.4e38f, -3.4e38f};
    float hc[2] = {0.f, 0.f}, c0c[2] = {0.f, 0.f};
    float ss[2] = {0.f, 0.f};
    // diag for col p0+ct*16+lm lives at global q = p0+ct*16+lm:
    const int qdd0 = p0 >> 8, wdd0 = (p0 >> 4) & 15;
    const int qdd1 = (p0 + 16) >> 8, wdd1 = ((p0 + 16) >> 4) & 15;

#pragma unroll 1
    for (int pass = 0; pass < 2; pass++) {
        AU cur, nxt;
#pragma unroll
        for (int g = 0; g < 8; g++)
            cur.d[g] = *(const i32x2*)(Abase + g * 512);

#pragma unroll 2
        for (int qs = 0; qs < NSTEP; qs++) {
            if (qs < NSTEP - 1) {
#pragma unroll
                for (int g = 0; g < 8; g++)
                    nxt.d[g] = *(const i32x2*)(Abase +
                        (size_t)(qs + 1) * 65536 + g * 512);
            }

            f32x4 acc[2] = {};
#pragma unroll
            for (int kb = 0; kb < 2; kb++)
#pragma unroll
                for (int ct = 0; ct < 2; ct++)
                    acc[ct] = __builtin_amdgcn_mfma_scale_f32_16x16x128_f8f6f4(
                        cur.v[kb], bf.v[ct][kb], acc[ct],
                        0, 0,                // cbsz=0 (e4m3), blgp=0 (e4m3)
                        0, 0x7f7f7f7f,       // scale_a sel, 1.0
                        0, 0x7f7f7f7f);      // scale_b sel, 1.0

            if (pass == 0) {
#pragma unroll
                for (int ct = 0; ct < 2; ct++)
#pragma unroll
                    for (int e = 0; e < 4; e++)
                        amax[ct] = fmaxf(amax[ct], acc[ct][e]);
            } else {
#pragma unroll
                for (int ct = 0; ct < 2; ct++) {
                    float s2 = 0.f;
#pragma unroll
                    for (int e = 0; e < 4; e++)
                        s2 += exp2f(fmaf(acc[ct][e], hc[ct], c0c[ct]));
                    ss[ct] += s2;
                }
                // diag: local row quad*4+e == lm  <=>  quad==lm>>2, e==lm&3
                if (qs == qdd0 && wv == wdd0 && quad == (lm >> 2))
                    dwl[lm] = exp2f(fmaf(acc[0][lm & 3], hc[0], c0c[0]));
                if (qs == qdd1 && wv == wdd1 && quad == (lm >> 2))
                    dwl[16 + lm] = exp2f(fmaf(acc[1][lm & 3], hc[1], c0c[1]));
            }

            if (qs < NSTEP - 1) cur = nxt;
        }

        if (pass == 0) {  // reduce col-maxes -> exp2 coefs per col
#pragma unroll
            for (int ct = 0; ct < 2; ct++) {
                amax[ct] = fmaxf(amax[ct], __shfl_xor(amax[ct], 16));
                amax[ct] = fmaxf(amax[ct], __shfl_xor(amax[ct], 32));
                if (quad == 0) redw[wv][ct * 16 + lm] = amax[ct];
            }
            __syncthreads();
            if (tid < 32) {
                float mx = redw[0][tid];
#pragma unroll
                for (int w2 = 1; w2 < 16; w2++) mx = fmaxf(mx, redw[w2][tid]);
                float mnv = (1.0f - mx) * 0.5f;            // column min of raw
                inv2s[tid] = 14.4269504f / (mnv + 1e-5f);
            }
            __syncthreads();
            {
                float i20 = inv2s[lm], i21 = inv2s[16 + lm];
                hc[0] = i20 * 0.5f; c0c[0] = 14.4269504f - hc[0];
                hc[1] = i21 * 0.5f; c0c[1] = 14.4269504f - hc[1];
            }
        }
    }

    // final: S per col, then partial loss = sum_c dwl[c]/S[c], one atomicAdd
#pragma unroll
    for (int ct = 0; ct < 2; ct++) {
        ss[ct] += __shfl_xor(ss[ct], 16);
        ss[ct] += __shfl_xor(ss[ct], 32);
        if (quad == 0) redw[wv][ct * 16 + lm] = ss[ct];
    }
    __syncthreads();
    if (tid < 32) {
        float s = 0.f;
#pragma unroll
        for (int w2 = 0; w2 < 16; w2++) s += redw[w2][tid];
        float part = dwl[tid] / s;
        part += __shfl_xor(part, 1);
        part += __shfl_xor(part, 2);
        part += __shfl_xor(part, 4);
        part += __shfl_xor(part, 8);
        part += __shfl_xor(part, 16);
        if (tid == 0) atomicAdd(&loss_acc[n], part);
    }
}

// ---- kernel 4: loss = mean_n -log(0.5 + 0.5 * acc_n/P) ----
__global__ void finalize_kernel(const float* __restrict__ loss_acc,
                                float* __restrict__ out) {
    float m0 = 0.5f + 0.5f * (loss_acc[0] / (float)PP);
    float m1 = 0.5f + 0.5f * (loss_acc[1] / (float)PP);
    out[0] = 0.5f * (-logf(m0) - logf(m1));
}

extern "C" void kernel_launch(void* const* d_in, const int* in_sizes, int n_in,
                              void* d_out, int out_size, void* d_ws, size_t ws_size,
                              hipStream_t stream) {
    const float* I = (const float*)d_in[0];
    const float* T = (const float*)d_in[1];
    float* out = (float*)d_out;

    char* ws = (char*)d_ws;
    const size_t SZ_F8 = (size_t)NN * PP * CC;  // 2 MB each (fp8)
    char* InT = ws;
    char* TnT = ws + SZ_F8;
    float* meanT = (float*)(ws + 2 * SZ_F8);               // 1 KB
    float* loss_acc = (float*)(ws + 2 * SZ_F8 + 32768);    // 8 B

    mean_kernel<<<CC, 256, 0, stream>>>(T, meanT, loss_acc);
    normalize_kernel<<<dim3(PP / 32, NN, 2), 256, 0, stream>>>(I, T, meanT, InT, TnT);
    cx_strip<<<dim3(PP / 32, NN), 1024, 0, stream>>>(TnT, InT, loss_acc);
    finalize_kernel<<<1, 1, 0, stream>>>(loss_acc, out);
}